// Round 4
// baseline (246.127 us; speedup 1.0000x reference)
//
#include <hip/hip_runtime.h>
#include <math.h>

#define D        2048
#define E        64
#define NROWS    16384              // B*S = 4*4096

// ---------------- fused MFMA path geometry ----------------
#define ROWS_PB  16                 // token rows per block (all 4 waves share)
#define KSW      512                // K-slice per wave (4 waves cover K=2048)
#define NCHW     (KSW / 64)         // 8 chunks of 64 per wave
#define WCVT_BYTES ((size_t)2 * E * D * sizeof(unsigned short))   // 512 KB

// lo-term scaling: lo' = (v - fp16(v)) * 2^11  (keeps lo in fp16 NORMAL range).
// Recombine with 2^-11 / 2^-22.
#define LSCALE   2048.0f
#define S1       4.8828125e-4f            // 2^-11
#define S2       2.384185791015625e-7f    // 2^-22

typedef __attribute__((ext_vector_type(8))) _Float16 f16x8;
typedef __attribute__((ext_vector_type(4))) float f32x4;

union u4h8 { uint4 u; f16x8 h; };

__device__ __forceinline__ unsigned short f2h(float f) {
    union { _Float16 h; unsigned short u; } c;
    c.h = (_Float16)f;                 // v_cvt_f16_f32, RNE
    return c.u;
}
__device__ __forceinline__ float h2f(unsigned short u) {
    union { _Float16 h; unsigned short u; } c;
    c.u = u;
    return (float)c.h;
}

__device__ __forceinline__ f16x8 ld_b16(const unsigned short* p) {
    u4h8 c; c.u = *(const uint4*)p; return c.h;
}

// scale + split 8 consecutive fp32 into fp16 hi / lo' fragments (in-register)
__device__ __forceinline__ void split8(float4 A, float4 B, float f,
                                       f16x8& hi, f16x8& lo) {
    float v[8] = {A.x * f, A.y * f, A.z * f, A.w * f,
                  B.x * f, B.y * f, B.z * f, B.w * f};
    unsigned int hw[4], lw[4];
#pragma unroll
    for (int j = 0; j < 4; ++j) {
        const unsigned short h0 = f2h(v[2*j]);
        const unsigned short h1 = f2h(v[2*j+1]);
        const unsigned short l0 = f2h((v[2*j]   - h2f(h0)) * LSCALE);
        const unsigned short l1 = f2h((v[2*j+1] - h2f(h1)) * LSCALE);
        hw[j] = (unsigned int)h0 | ((unsigned int)h1 << 16);
        lw[j] = (unsigned int)l0 | ((unsigned int)l1 << 16);
    }
    u4h8 ch; ch.u = make_uint4(hw[0], hw[1], hw[2], hw[3]); hi = ch.h;
    u4h8 cl; cl.u = make_uint4(lw[0], lw[1], lw[2], lw[3]); lo = cl.h;
}

// ============ K0: split W (fp32) -> W_hi, W_lo' (fp16, RNE) =================
__global__ __launch_bounds__(256)
void w_cvt(const float* __restrict__ W,
           unsigned short* __restrict__ whi,
           unsigned short* __restrict__ wlo)
{
    const int i = (blockIdx.x * 256 + threadIdx.x) << 3;
    const float4 a = *(const float4*)(W + i);
    const float4 b = *(const float4*)(W + i + 4);
    float vv[8] = {a.x, a.y, a.z, a.w, b.x, b.y, b.z, b.w};
    unsigned int hw[4], lw[4];
#pragma unroll
    for (int j = 0; j < 4; ++j) {
        const unsigned short h0 = f2h(vv[2*j]);
        const unsigned short h1 = f2h(vv[2*j+1]);
        const unsigned short l0 = f2h((vv[2*j]   - h2f(h0)) * LSCALE);
        const unsigned short l1 = f2h((vv[2*j+1] - h2f(h1)) * LSCALE);
        hw[j] = (unsigned int)h0 | ((unsigned int)h1 << 16);
        lw[j] = (unsigned int)l0 | ((unsigned int)l1 << 16);
    }
    *(uint4*)(whi + i) = make_uint4(hw[0], hw[1], hw[2], hw[3]);
    *(uint4*)(wlo + i) = make_uint4(lw[0], lw[1], lw[2], lw[3]);
}

// ============ K1: barrier-free fp16-split MFMA GEMM + softmax + top2 ========
// Grid 1024 x 256 thr (4 waves). All 4 waves: same 16 token rows x 64 experts,
// DISJOINT K-quarters (512 each) -> x read exactly once chip-wide, no LDS and
// NO BARRIERS in the main loop. Each wave free-runs:
//   A: lane (fr,fq) loads x[row fr][k+8fq..+8] fp32 from global (2-chunk-deep
//      register prefetch), scales + fp16 hi/lo'-splits in-register.
//   B: W hi/lo fragments straight from global (L2-resident 512 KB), as r3.
// Accumulators by scale class: hh (x1), hl+lh (x2^-11), ll (x2^-22), 4 col
// tiles. End: per-wave fp32 partial logits -> own LDS slice, 1 barrier,
// 4-way reduce, 1 barrier, verified softmax/top-2 epilogue.
__global__ __launch_bounds__(256, 2)
void moe_fused(const float* __restrict__ x,
               const unsigned short* __restrict__ whi,
               const unsigned short* __restrict__ wlo,
               const float* __restrict__ scond,
               const int* __restrict__ sidx,
               const float* __restrict__ noise,
               float* __restrict__ dispatch,
               float* __restrict__ probs,
               float* __restrict__ sel)
{
    __shared__ float lgs[4 * 16 * 68];          // 4 slices x [16][68] = 17408 B

    const int t = threadIdx.x;
    const int l = t & 63;
    const int w = t >> 6;

    const float factor = 1.0f + 0.1f * scond[sidx[0]];

    const int fr = l & 15;                       // fragment row lane
    const int fq = l >> 4;                       // fragment k-quad lane
    const int rowG0 = blockIdx.x * ROWS_PB;
    const int kb = w << 9;                       // wave K-base: w*512

    const float* xg = x + (size_t)(rowG0 + fr) * D + kb + (fq << 3);
    const unsigned short* bgh = whi + fr * D + kb + (fq << 3);
    const unsigned short* bgl = wlo + fr * D + kb + (fq << 3);

    f32x4 acch[4], accm[4], accl[4];
#pragma unroll
    for (int ct = 0; ct < 4; ++ct) {
        acch[ct] = (f32x4){0.f,0.f,0.f,0.f};
        accm[ct] = (f32x4){0.f,0.f,0.f,0.f};
        accl[ct] = (f32x4){0.f,0.f,0.f,0.f};
    }

    // A fp32 pipeline: current chunk (a*) + next chunk (p*); 2-deep in flight
    float4 a0 = *(const float4*)(xg +  0), a1 = *(const float4*)(xg +  4);
    float4 a2 = *(const float4*)(xg + 32), a3 = *(const float4*)(xg + 36);
    float4 p0 = *(const float4*)(xg + 64), p1 = *(const float4*)(xg + 68);
    float4 p2 = *(const float4*)(xg + 96), p3 = *(const float4*)(xg + 100);

#pragma unroll
    for (int c = 0; c < NCHW; ++c) {
        f16x8 ah0, al0, ah1, al1;
        split8(a0, a1, factor, ah0, al0);        // ks=0 fragment
        split8(a2, a3, factor, ah1, al1);        // ks=1 fragment
        a0 = p0; a1 = p1; a2 = p2; a3 = p3;
        if (c + 2 < NCHW) {
            const float* xp = xg + (c + 2) * 64;
            p0 = *(const float4*)(xp +  0); p1 = *(const float4*)(xp +  4);
            p2 = *(const float4*)(xp + 32); p3 = *(const float4*)(xp + 36);
        }
        const int ko0 = c * 64;
#pragma unroll
        for (int ks = 0; ks < 2; ++ks) {
            const int ko = ko0 + ks * 32;
            const f16x8 ah = ks ? ah1 : ah0;
            const f16x8 al = ks ? al1 : al0;
#pragma unroll
            for (int ct = 0; ct < 4; ++ct) {
                const f16x8 bh = ld_b16(bgh + ct * (16 * D) + ko);
                const f16x8 bl = ld_b16(bgl + ct * (16 * D) + ko);
                acch[ct] = __builtin_amdgcn_mfma_f32_16x16x32_f16(ah, bh, acch[ct], 0, 0, 0);
                accm[ct] = __builtin_amdgcn_mfma_f32_16x16x32_f16(ah, bl, accm[ct], 0, 0, 0);
                accm[ct] = __builtin_amdgcn_mfma_f32_16x16x32_f16(al, bh, accm[ct], 0, 0, 0);
                accl[ct] = __builtin_amdgcn_mfma_f32_16x16x32_f16(al, bl, accl[ct], 0, 0, 0);
            }
        }
    }

    // ---- per-wave partial logits -> own LDS slice (verified C/D mapping) ----
    float* slice = lgs + w * (16 * 68);
#pragma unroll
    for (int ct = 0; ct < 4; ++ct)
#pragma unroll
        for (int j = 0; j < 4; ++j)
            slice[((fq << 2) + j) * 68 + (ct << 4) + fr] =
                acch[ct][j] + S1 * accm[ct][j] + S2 * accl[ct][j];

    __syncthreads();

    // ---- reduce 4 K-slices (owner thread: row t>>4, cols (t&15)*4..+4) ----
    {
        const int o = (t >> 4) * 68 + ((t & 15) << 2);
        const float4 v0 = *(const float4*)&lgs[o];
        const float4 v1 = *(const float4*)&lgs[1 * 16 * 68 + o];
        const float4 v2 = *(const float4*)&lgs[2 * 16 * 68 + o];
        const float4 v3 = *(const float4*)&lgs[3 * 16 * 68 + o];
        float4 r;
        r.x = (v0.x + v1.x) + (v2.x + v3.x);
        r.y = (v0.y + v1.y) + (v2.y + v3.y);
        r.z = (v0.z + v1.z) + (v2.z + v3.z);
        r.w = (v0.w + v1.w) + (v2.w + v3.w);
        *(float4*)&lgs[o] = r;                   // owner-only read+write: safe
    }
    __syncthreads();

    // ---- verified softmax/top-2 epilogue: 4 rows per wave ----
    const int r0 = w << 2;
#pragma unroll
    for (int i = 0; i < 4; ++i) {
        const int G = rowG0 + r0 + i;
        const float v = lgs[(r0 + i) * 68 + l] + 0.1f * noise[(size_t)G * E + l];

        float m = v;
#pragma unroll
        for (int off = 32; off > 0; off >>= 1)
            m = fmaxf(m, __shfl_xor(m, off, 64));
        const float p = expf(v - m);
        float s = p;
#pragma unroll
        for (int off = 32; off > 0; off >>= 1)
            s += __shfl_xor(s, off, 64);
        const float prob = p / s;
        probs[(size_t)G * E + l] = prob;

        float bv = prob; int bi = l;
#pragma unroll
        for (int off = 32; off > 0; off >>= 1) {
            const float ov = __shfl_xor(bv, off, 64);
            const int   oi = __shfl_xor(bi, off, 64);
            if (ov > bv || (ov == bv && oi < bi)) { bv = ov; bi = oi; }
        }
        float cv = (l == bi) ? -INFINITY : prob;
        int ci = l;
#pragma unroll
        for (int off = 32; off > 0; off >>= 1) {
            const float ov = __shfl_xor(cv, off, 64);
            const int   oi = __shfl_xor(ci, off, 64);
            if (ov > cv || (ov == cv && oi < ci)) { cv = ov; ci = oi; }
        }

        const float sum2 = bv + cv;
        float dval = 0.f;
        if (l == bi) dval = bv / sum2;
        if (l == ci) dval = cv / sum2;
        dispatch[(size_t)G * E + l] = dval;

        if (l == 0) {
            float2 sv; sv.x = (float)bi; sv.y = (float)ci;
            *(float2*)(sel + (size_t)G * 2) = sv;
        }
    }
}

// ================== Fallback pair (round-2, known-good) =====================
__global__ __launch_bounds__(256)
void gemm_r2(const float* __restrict__ x, const float* __restrict__ W,
             const float* __restrict__ scond, const float* __restrict__ noise,
             const int* __restrict__ sidx, float* __restrict__ logits_out)
{
    __shared__ float4 xsb[32][17];
    __shared__ float4 wsh[64][16];
    const int tid = threadIdx.x;
    const int rowBase = blockIdx.x * 32;
    const float factor = 1.0f + 0.1f * scond[sidx[0]];
    const int xk = tid & 15, xr = tid >> 4, we = tid & 63, wk = tid >> 6;
    const int eg = tid & 15, rg = tid >> 4, e0 = eg << 2;
    float acc[2][4];
#pragma unroll
    for (int i = 0; i < 2; ++i)
#pragma unroll
        for (int j = 0; j < 4; ++j) acc[i][j] = 0.f;
    const float* xg = x + (size_t)rowBase * D;
    float4 xb[2], wb[4];
#pragma unroll
    for (int i = 0; i < 2; ++i)
        xb[i] = *(const float4*)(xg + (xr + 16 * i) * D + (xk << 2));
#pragma unroll
    for (int j = 0; j < 4; ++j)
        wb[j] = *(const float4*)(W + we * D + (wk << 4) + (j << 2));
    for (int t = 0; t < 32; ++t) {
#pragma unroll
        for (int i = 0; i < 2; ++i) {
            float4 v = xb[i];
            v.x *= factor; v.y *= factor; v.z *= factor; v.w *= factor;
            xsb[xr + 16 * i][xk] = v;
        }
        float* wsf = (float*)wsh;
#pragma unroll
        for (int j = 0; j < 4; ++j) {
            const int kk = (wk << 4) + (j << 2);
            wsf[(kk + 0) * E + we] = wb[j].x;
            wsf[(kk + 1) * E + we] = wb[j].y;
            wsf[(kk + 2) * E + we] = wb[j].z;
            wsf[(kk + 3) * E + we] = wb[j].w;
        }
        __syncthreads();
        if (t + 1 < 32) {
            const int k0 = (t + 1) * 64;
#pragma unroll
            for (int i = 0; i < 2; ++i)
                xb[i] = *(const float4*)(xg + (xr + 16 * i) * D + k0 + (xk << 2));
#pragma unroll
            for (int j = 0; j < 4; ++j)
                wb[j] = *(const float4*)(W + we * D + k0 + (wk << 4) + (j << 2));
        }
#pragma unroll
        for (int kg = 0; kg < 16; ++kg) {
            float4 xv[2], wv[4];
#pragma unroll
            for (int i = 0; i < 2; ++i) xv[i] = xsb[rg + 16 * i][kg];
#pragma unroll
            for (int c = 0; c < 4; ++c) wv[c] = wsh[(kg << 2) + c][eg];
#pragma unroll
            for (int i = 0; i < 2; ++i) {
                const float x0 = xv[i].x, x1 = xv[i].y, x2 = xv[i].z, x3 = xv[i].w;
                acc[i][0] += x0 * wv[0].x; acc[i][1] += x0 * wv[0].y;
                acc[i][2] += x0 * wv[0].z; acc[i][3] += x0 * wv[0].w;
                acc[i][0] += x1 * wv[1].x; acc[i][1] += x1 * wv[1].y;
                acc[i][2] += x1 * wv[1].z; acc[i][3] += x1 * wv[1].w;
                acc[i][0] += x2 * wv[2].x; acc[i][1] += x2 * wv[2].y;
                acc[i][2] += x2 * wv[2].z; acc[i][3] += x2 * wv[2].w;
                acc[i][0] += x3 * wv[3].x; acc[i][1] += x3 * wv[3].y;
                acc[i][2] += x3 * wv[3].z; acc[i][3] += x3 * wv[3].w;
            }
        }
        __syncthreads();
    }
#pragma unroll
    for (int i = 0; i < 2; ++i) {
        const int gRow = rowBase + rg + 16 * i;
        const float4 nz = *(const float4*)(noise + (size_t)gRow * E + e0);
        float4 o;
        o.x = acc[i][0] + 0.1f * nz.x; o.y = acc[i][1] + 0.1f * nz.y;
        o.z = acc[i][2] + 0.1f * nz.z; o.w = acc[i][3] + 0.1f * nz.w;
        *(float4*)(logits_out + (size_t)gRow * E + e0) = o;
    }
}

__global__ __launch_bounds__(256)
void topk_r2(float* __restrict__ probs, float* __restrict__ dispatch,
             float* __restrict__ sel)
{
    const int lane = threadIdx.x & 63;
    const int wave = threadIdx.x >> 6;
    const int row  = blockIdx.x * 4 + wave;
    const float v = probs[(size_t)row * E + lane];
    float m = v;
#pragma unroll
    for (int off = 32; off > 0; off >>= 1)
        m = fmaxf(m, __shfl_xor(m, off, 64));
    const float p = expf(v - m);
    float s = p;
#pragma unroll
    for (int off = 32; off > 0; off >>= 1)
        s += __shfl_xor(s, off, 64);
    const float prob = p / s;
    probs[(size_t)row * E + lane] = prob;
    float bv = prob; int bi = lane;
#pragma unroll
    for (int off = 32; off > 0; off >>= 1) {
        const float ov = __shfl_xor(bv, off, 64);
        const int   oi = __shfl_xor(bi, off, 64);
        if (ov > bv || (ov == bv && oi < bi)) { bv = ov; bi = oi; }
    }
    float cv = (lane == bi) ? -INFINITY : prob;
    int ci = lane;
#pragma unroll
    for (int off = 32; off > 0; off >>= 1) {
        const float ov = __shfl_xor(cv, off, 64);
        const int   oi = __shfl_xor(ci, off, 64);
        if (ov > cv || (ov == cv && oi < ci)) { cv = ov; ci = oi; }
    }
    const float sum2 = bv + cv;
    float dval = 0.f;
    if (lane == bi) dval = bv / sum2;
    if (lane == ci) dval = cv / sum2;
    dispatch[(size_t)row * E + lane] = dval;
    if (lane == 0) {
        float2 sv; sv.x = (float)bi; sv.y = (float)ci;
        *(float2*)(sel + (size_t)row * 2) = sv;
    }
}

extern "C" void kernel_launch(void* const* d_in, const int* in_sizes, int n_in,
                              void* d_out, int out_size, void* d_ws, size_t ws_size,
                              hipStream_t stream) {
    const float* x     = (const float*)d_in[0];
    const float* W     = (const float*)d_in[1];
    const float* scond = (const float*)d_in[2];
    const float* noise = (const float*)d_in[3];
    const int*   sidx  = (const int*)d_in[4];

    float* out      = (float*)d_out;
    float* dispatch = out;
    float* probs    = out + (size_t)NROWS * E;
    float* sel      = out + 2 * (size_t)NROWS * E;

    if (ws_size >= WCVT_BYTES) {
        unsigned short* whi = (unsigned short*)d_ws;
        unsigned short* wlo = whi + (size_t)E * D;
        w_cvt<<<dim3(64), dim3(256), 0, stream>>>(W, whi, wlo);
        moe_fused<<<dim3(NROWS / ROWS_PB), dim3(256), 0, stream>>>(
            x, whi, wlo, scond, sidx, noise, dispatch, probs, sel);
    } else {
        gemm_r2<<<dim3(NROWS / 32), dim3(256), 0, stream>>>(
            x, W, scond, noise, sidx, probs);
        topk_r2<<<dim3(NROWS / 4), dim3(256), 0, stream>>>(
            probs, dispatch, sel);
    }
}